// Round 4
// baseline (1369.703 us; speedup 1.0000x reference)
//
#include <hip/hip_runtime.h>
#include <stdint.h>

static constexpr int kN   = 50000;   // nodes
static constexpr int kCap = 64;      // adjacency capacity per node (Poisson(12) tail @64 ~ 1e-25)

// ---------------- threefry2x32-20 (verified vs Random123 KAT) ----------------
__device__ __forceinline__ uint32_t rotl32(uint32_t v, uint32_t r) {
  return (v << r) | (v >> (32u - r));
}

__device__ __forceinline__ uint2 threefry2x32(uint32_t k0, uint32_t k1,
                                              uint32_t x0, uint32_t x1) {
  const uint32_t k2 = k0 ^ k1 ^ 0x1BD11BDAu;
  x0 += k0; x1 += k1;
#define TFR(r) { x0 += x1; x1 = rotl32(x1, r); x1 ^= x0; }
  TFR(13u) TFR(15u) TFR(26u) TFR(6u)
  x0 += k1; x1 += k2 + 1u;
  TFR(17u) TFR(29u) TFR(16u) TFR(24u)
  x0 += k2; x1 += k0 + 2u;
  TFR(13u) TFR(15u) TFR(26u) TFR(6u)
  x0 += k0; x1 += k1 + 3u;
  TFR(17u) TFR(29u) TFR(16u) TFR(24u)
  x0 += k1; x1 += k2 + 4u;
  TFR(13u) TFR(15u) TFR(26u) TFR(6u)
  x0 += k2; x1 += k0 + 5u;
#undef TFR
  return make_uint2(x0, x1);
}

// JAX dropout bit (jax_threefry_partitionable default): keep iff MSB==0 of
// out0^out1 of threefry((0,42), (0, j)).
__device__ __forceinline__ bool drop_elem(uint32_t j) {
  const uint2 r = threefry2x32(0u, 42u, 0u, j);
  return ((r.x ^ r.y) >> 31) != 0u;
}

// round-to-nearest-even f32 -> bf16 (upper 16 bits)
__device__ __forceinline__ uint32_t bf16_rtne(float f) {
  uint32_t u = __float_as_uint(f);
  u += 0x7fffu + ((u >> 16) & 1u);
  return u >> 16;
}
__device__ __forceinline__ uint32_t pack_bf16x2(float lo, float hi) {
  return bf16_rtne(lo) | (bf16_rtne(hi) << 16);
}
__device__ __forceinline__ float unpk_lo(uint32_t u) { return __uint_as_float(u << 16); }
__device__ __forceinline__ float unpk_hi(uint32_t u) { return __uint_as_float(u & 0xffff0000u); }

// ---------------- adjacency build: adj[d*64 + slot] = src ----------------
__global__ __launch_bounds__(256) void build_adj(
    const int* __restrict__ src, const int* __restrict__ dst,
    int* __restrict__ cnt, int* __restrict__ adj, int E) {
  int e = blockIdx.x * 256 + threadIdx.x;
  if (e >= E) return;
  int d = dst[e];
  int slot = atomicAdd(&cnt[d], 1);
  if (slot < kCap) adj[d * kCap + slot] = src[e];
}

// ---------------- fused layer 1 ----------------
// h[n] = dropout(relu((x[n] + sum_{s in adj[n]} x[s]) @ W1 + b1))
// One node per wave. Lane l holds input features {2l, 2l+1} (float2 loads).
// W1 in LDS as packed bf16: Wp[kk*64+l] = uint2{ pack(W[2kk][2l],W[2kk][2l+1]),
//                                                pack(W[2kk+1][2l],W[2kk+1][2l+1]) }.
// Input broadcast via readlane (SGPR operand) -> no bpermute traffic.
__global__ __launch_bounds__(256, 5) void gin_fused1(
    const float* __restrict__ x, const int* __restrict__ adj,
    const int* __restrict__ cnt, const float* __restrict__ W1,
    const float* __restrict__ b1, float* __restrict__ h) {
  __shared__ uint2 Wp[64 * 64];  // 32 KB
  for (int idx = threadIdx.x; idx < 64 * 64; idx += 256) {
    const int kk = idx >> 6, l = idx & 63;
    const float2 a = *reinterpret_cast<const float2*>(W1 + (size_t)(2 * kk) * 128 + 2 * l);
    const float2 b = *reinterpret_cast<const float2*>(W1 + (size_t)(2 * kk + 1) * 128 + 2 * l);
    Wp[idx] = make_uint2(pack_bf16x2(a.x, a.y), pack_bf16x2(b.x, b.y));
  }
  __syncthreads();

  const int lane = threadIdx.x & 63;
  const int wid  = threadIdx.x >> 6;  // 0..3
  const float2 bias = *reinterpret_cast<const float2*>(b1 + 2 * lane);

  for (int n = blockIdx.x * 4 + wid; n < kN; n += gridDim.x * 4) {
    const size_t rb = (size_t)n * 128;
    // one-shot adjacency load: lane l holds adj[n*64+l]
    const int va = adj[(size_t)n * kCap + lane];
    int d = cnt[n];
    d = __builtin_amdgcn_readfirstlane(d);
    if (d > kCap) d = kCap;

    // gather: self + neighbors, 4 independent partial sums
    float2 s0 = *reinterpret_cast<const float2*>(x + rb + 2 * lane);
    float2 s1 = make_float2(0.f, 0.f), s2 = make_float2(0.f, 0.f), s3 = make_float2(0.f, 0.f);
    int e = 0;
    for (; e + 4 <= d; e += 4) {
      const int a0 = __builtin_amdgcn_readlane(va, e);
      const int a1 = __builtin_amdgcn_readlane(va, e + 1);
      const int a2 = __builtin_amdgcn_readlane(va, e + 2);
      const int a3 = __builtin_amdgcn_readlane(va, e + 3);
      const float2 v0 = *reinterpret_cast<const float2*>(x + (size_t)a0 * 128 + 2 * lane);
      const float2 v1 = *reinterpret_cast<const float2*>(x + (size_t)a1 * 128 + 2 * lane);
      const float2 v2 = *reinterpret_cast<const float2*>(x + (size_t)a2 * 128 + 2 * lane);
      const float2 v3 = *reinterpret_cast<const float2*>(x + (size_t)a3 * 128 + 2 * lane);
      s0.x += v0.x; s0.y += v0.y; s1.x += v1.x; s1.y += v1.y;
      s2.x += v2.x; s2.y += v2.y; s3.x += v3.x; s3.y += v3.y;
    }
    for (; e < d; ++e) {
      const int a0 = __builtin_amdgcn_readlane(va, e);
      const float2 v0 = *reinterpret_cast<const float2*>(x + (size_t)a0 * 128 + 2 * lane);
      s1.x += v0.x; s1.y += v0.y;
    }
    const float rx = (s0.x + s1.x) + (s2.x + s3.x);
    const float ry = (s0.y + s1.y) + (s2.y + s3.y);

    // GEMM: acc = features {2*lane, 2*lane+1}
    float ax = bias.x, ay = bias.y;
#pragma unroll
    for (int kk = 0; kk < 64; ++kk) {
      const uint2 w = Wp[kk * 64 + lane];           // ds_read_b64, 2-way alias (free)
      const float v0 = __int_as_float(__builtin_amdgcn_readlane(__float_as_int(rx), kk));
      const float v1 = __int_as_float(__builtin_amdgcn_readlane(__float_as_int(ry), kk));
      ax = fmaf(v0, unpk_lo(w.x), ax);
      ay = fmaf(v0, unpk_hi(w.x), ay);
      ax = fmaf(v1, unpk_lo(w.y), ax);
      ay = fmaf(v1, unpk_hi(w.y), ay);
    }

    ax = fmaxf(ax, 0.0f); ay = fmaxf(ay, 0.0f);
    const uint32_t j = (uint32_t)n * 128u + 2u * (uint32_t)lane;
    float2 o;
    o.x = drop_elem(j)      ? 0.0f : ax * 2.0f;
    o.y = drop_elem(j + 1u) ? 0.0f : ay * 2.0f;
    *reinterpret_cast<float2*>(h + rb + 2 * lane) = o;
  }
}

// ---------------- fused layer 2 ----------------
// out[n] = (h[n] + sum_{s in adj[n]} h[s]) @ W2 + b2
// Lane l holds input features {2l,2l+1} and output feature l.
// W2 in LDS f32 pairs: Wl[kk*64+l] = float2(W2[2kk][l], W2[2kk+1][l]).
__global__ __launch_bounds__(256, 5) void gin_fused2(
    const float* __restrict__ h, const int* __restrict__ adj,
    const int* __restrict__ cnt, const float* __restrict__ W2,
    const float* __restrict__ b2, float* __restrict__ out) {
  __shared__ float2 Wl[64 * 64];  // 32 KB
  for (int idx = threadIdx.x; idx < 64 * 64; idx += 256) {
    const int kk = idx >> 6, l = idx & 63;
    Wl[idx] = make_float2(W2[(size_t)(2 * kk) * 64 + l], W2[(size_t)(2 * kk + 1) * 64 + l]);
  }
  __syncthreads();

  const int lane = threadIdx.x & 63;
  const int wid  = threadIdx.x >> 6;
  const float bias = b2[lane];

  for (int n = blockIdx.x * 4 + wid; n < kN; n += gridDim.x * 4) {
    const size_t rb = (size_t)n * 128;
    const int va = adj[(size_t)n * kCap + lane];
    int d = cnt[n];
    d = __builtin_amdgcn_readfirstlane(d);
    if (d > kCap) d = kCap;

    float2 s0 = *reinterpret_cast<const float2*>(h + rb + 2 * lane);
    float2 s1 = make_float2(0.f, 0.f), s2 = make_float2(0.f, 0.f), s3 = make_float2(0.f, 0.f);
    int e = 0;
    for (; e + 4 <= d; e += 4) {
      const int a0 = __builtin_amdgcn_readlane(va, e);
      const int a1 = __builtin_amdgcn_readlane(va, e + 1);
      const int a2 = __builtin_amdgcn_readlane(va, e + 2);
      const int a3 = __builtin_amdgcn_readlane(va, e + 3);
      const float2 v0 = *reinterpret_cast<const float2*>(h + (size_t)a0 * 128 + 2 * lane);
      const float2 v1 = *reinterpret_cast<const float2*>(h + (size_t)a1 * 128 + 2 * lane);
      const float2 v2 = *reinterpret_cast<const float2*>(h + (size_t)a2 * 128 + 2 * lane);
      const float2 v3 = *reinterpret_cast<const float2*>(h + (size_t)a3 * 128 + 2 * lane);
      s0.x += v0.x; s0.y += v0.y; s1.x += v1.x; s1.y += v1.y;
      s2.x += v2.x; s2.y += v2.y; s3.x += v3.x; s3.y += v3.y;
    }
    for (; e < d; ++e) {
      const int a0 = __builtin_amdgcn_readlane(va, e);
      const float2 v0 = *reinterpret_cast<const float2*>(h + (size_t)a0 * 128 + 2 * lane);
      s1.x += v0.x; s1.y += v0.y;
    }
    const float rx = (s0.x + s1.x) + (s2.x + s3.x);
    const float ry = (s0.y + s1.y) + (s2.y + s3.y);

    float acc = bias;
#pragma unroll
    for (int kk = 0; kk < 64; ++kk) {
      const float2 w = Wl[kk * 64 + lane];          // ds_read_b64
      const float v0 = __int_as_float(__builtin_amdgcn_readlane(__float_as_int(rx), kk));
      const float v1 = __int_as_float(__builtin_amdgcn_readlane(__float_as_int(ry), kk));
      acc = fmaf(v0, w.x, acc);
      acc = fmaf(v1, w.y, acc);
    }

    out[(size_t)n * 64 + lane] = acc;
  }
}

// ---------------- launch ----------------
extern "C" void kernel_launch(void* const* d_in, const int* in_sizes, int n_in,
                              void* d_out, int out_size, void* d_ws, size_t ws_size,
                              hipStream_t stream) {
  const float* x  = (const float*)d_in[0];
  const int*   ei = (const int*)d_in[1];
  const float* W1 = (const float*)d_in[2];
  const float* b1 = (const float*)d_in[3];
  const float* W2 = (const float*)d_in[4];
  const float* b2 = (const float*)d_in[5];
  float* out = (float*)d_out;

  const int E = in_sizes[1] / 2;  // edge_index is (2, E), int32 on device
  const int* src = ei;
  const int* dst = ei + E;

  int*   cnt = (int*)d_ws;                         // 50000 ints
  int*   adj = cnt + kN;                           // 50000*64 ints = 12.8 MB
  float* h   = (float*)(adj + (size_t)kN * kCap);  // 50000*128 f32 = 25.6 MB

  hipMemsetAsync(cnt, 0, (size_t)kN * sizeof(int), stream);
  build_adj<<<(E + 255) / 256, 256, 0, stream>>>(src, dst, cnt, adj, E);
  gin_fused1<<<2048, 256, 0, stream>>>(x, adj, cnt, W1, b1, h);
  gin_fused2<<<2048, 256, 0, stream>>>(h, adj, cnt, W2, b2, out);
}

// Round 5
// 262.940 us; speedup vs baseline: 5.2092x; 5.2092x over previous
//
#include <hip/hip_runtime.h>
#include <stdint.h>

static constexpr int kN   = 50000;   // nodes
static constexpr int kCap = 64;      // adjacency capacity per node (Poisson(12) tail @64 ~ 1e-25)

// ---------------- threefry2x32-20 (verified vs Random123 KAT) ----------------
__device__ __forceinline__ uint32_t rotl32(uint32_t v, uint32_t r) {
  return (v << r) | (v >> (32u - r));
}

__device__ __forceinline__ uint2 threefry2x32(uint32_t k0, uint32_t k1,
                                              uint32_t x0, uint32_t x1) {
  const uint32_t k2 = k0 ^ k1 ^ 0x1BD11BDAu;
  x0 += k0; x1 += k1;
#define TFR(r) { x0 += x1; x1 = rotl32(x1, r); x1 ^= x0; }
  TFR(13u) TFR(15u) TFR(26u) TFR(6u)
  x0 += k1; x1 += k2 + 1u;
  TFR(17u) TFR(29u) TFR(16u) TFR(24u)
  x0 += k2; x1 += k0 + 2u;
  TFR(13u) TFR(15u) TFR(26u) TFR(6u)
  x0 += k0; x1 += k1 + 3u;
  TFR(17u) TFR(29u) TFR(16u) TFR(24u)
  x0 += k1; x1 += k2 + 4u;
  TFR(13u) TFR(15u) TFR(26u) TFR(6u)
  x0 += k2; x1 += k0 + 5u;
#undef TFR
  return make_uint2(x0, x1);
}

// JAX dropout bit (jax_threefry_partitionable default): keep iff MSB==0 of
// out0^out1 of threefry((0,42), (0, j)).
__device__ __forceinline__ bool drop_elem(uint32_t j) {
  const uint2 r = threefry2x32(0u, 42u, 0u, j);
  return ((r.x ^ r.y) >> 31) != 0u;
}

// ---------------- adjacency build: adj[d*64 + slot] = src ----------------
__global__ __launch_bounds__(256) void build_adj(
    const int* __restrict__ src, const int* __restrict__ dst,
    int* __restrict__ cnt, int* __restrict__ adj, int E) {
  int e = blockIdx.x * 256 + threadIdx.x;
  if (e >= E) return;
  int d = dst[e];
  int slot = atomicAdd(&cnt[d], 1);
  if (slot < kCap) adj[d * kCap + slot] = src[e];
}

// ---------------- dense GEMM 1: z1 = x @ W1  (50000x128 @ 128x128) ----------------
// Block 256 = 4 waves; each wave computes 4 nodes. Lane holds output features
// {2l, 2l+1}. W1 in LDS as float4: Wq[kk*64+l] = {W[2kk][2l], W[2kk][2l+1],
// W[2kk+1][2l], W[2kk+1][2l+1]}. Input row broadcast via v_readlane.
__global__ __launch_bounds__(256, 2) void gemm1(
    const float* __restrict__ x, const float* __restrict__ W1,
    float* __restrict__ z1) {
  __shared__ float4 Wq[64 * 64];  // 64 KB
  for (int idx = threadIdx.x; idx < 64 * 64; idx += 256) {
    const int kk = idx >> 6, l = idx & 63;
    const float2 a = *reinterpret_cast<const float2*>(W1 + (size_t)(2 * kk) * 128 + 2 * l);
    const float2 b = *reinterpret_cast<const float2*>(W1 + (size_t)(2 * kk + 1) * 128 + 2 * l);
    Wq[idx] = make_float4(a.x, a.y, b.x, b.y);
  }
  __syncthreads();

  const int lane = threadIdx.x & 63;
  const int wid  = threadIdx.x >> 6;
  const int n0 = (blockIdx.x * 4 + wid) * 4;  // 3125 blocks * 16 = 50000 exact

  float rx[4], ry[4];
#pragma unroll
  for (int i = 0; i < 4; ++i) {
    const float2 v = *reinterpret_cast<const float2*>(x + (size_t)(n0 + i) * 128 + 2 * lane);
    rx[i] = v.x; ry[i] = v.y;
  }
  float ax[4] = {0.f, 0.f, 0.f, 0.f}, ay[4] = {0.f, 0.f, 0.f, 0.f};
#pragma unroll
  for (int kk = 0; kk < 64; ++kk) {
    const float4 w = Wq[kk * 64 + lane];
#pragma unroll
    for (int i = 0; i < 4; ++i) {
      const float v0 = __int_as_float(__builtin_amdgcn_readlane(__float_as_int(rx[i]), kk));
      const float v1 = __int_as_float(__builtin_amdgcn_readlane(__float_as_int(ry[i]), kk));
      ax[i] = fmaf(v0, w.x, ax[i]); ay[i] = fmaf(v0, w.y, ay[i]);
      ax[i] = fmaf(v1, w.z, ax[i]); ay[i] = fmaf(v1, w.w, ay[i]);
    }
  }
#pragma unroll
  for (int i = 0; i < 4; ++i)
    *reinterpret_cast<float2*>(z1 + (size_t)(n0 + i) * 128 + 2 * lane) = make_float2(ax[i], ay[i]);
}

// ---------------- agg1: h = dropout(relu(z1[n] + sum z1[adj] + b1)) ----------------
// Pure gather, no LDS. One node per wave, 12500 blocks x 4 waves = 50000.
// 16 neighbor loads in flight (zero-row padding for e>=d). 32 waves/CU target.
__global__ __launch_bounds__(256, 8) void agg_relu_drop(
    const float* __restrict__ z1, const int* __restrict__ adj,
    const int* __restrict__ cnt, const float* __restrict__ b1,
    const float* __restrict__ zrow, float* __restrict__ h) {
  const int lane = threadIdx.x & 63;
  const int wid  = threadIdx.x >> 6;
  const int n = blockIdx.x * 4 + wid;

  const int va = adj[(size_t)n * kCap + lane];
  int d = __builtin_amdgcn_readfirstlane(cnt[n]);
  if (d > kCap) d = kCap;

  float2 a0 = *reinterpret_cast<const float2*>(z1 + (size_t)n * 128 + 2 * lane);  // self
  float2 a1 = make_float2(0.f, 0.f), a2 = make_float2(0.f, 0.f), a3 = make_float2(0.f, 0.f);

  int e = 0;
  while (e < d) {
#pragma unroll
    for (int j = 0; j < 16; ++j) {
      const int ee = e + j;
      const int idx = __builtin_amdgcn_readlane(va, ee);
      const float* base = (ee < d) ? (z1 + (size_t)idx * 128) : zrow;  // scalar select
      const float2 v = *reinterpret_cast<const float2*>(base + 2 * lane);
      if ((j & 3) == 0)      { a0.x += v.x; a0.y += v.y; }
      else if ((j & 3) == 1) { a1.x += v.x; a1.y += v.y; }
      else if ((j & 3) == 2) { a2.x += v.x; a2.y += v.y; }
      else                   { a3.x += v.x; a3.y += v.y; }
    }
    e += 16;
  }

  const float sx = (a0.x + a1.x) + (a2.x + a3.x);
  const float sy = (a0.y + a1.y) + (a2.y + a3.y);
  const float2 bb = *reinterpret_cast<const float2*>(b1 + 2 * lane);
  const float vx = fmaxf(sx + bb.x, 0.0f);
  const float vy = fmaxf(sy + bb.y, 0.0f);

  const uint32_t j0 = (uint32_t)n * 128u + 2u * (uint32_t)lane;
  float2 o;
  o.x = drop_elem(j0)      ? 0.0f : vx * 2.0f;
  o.y = drop_elem(j0 + 1u) ? 0.0f : vy * 2.0f;
  *reinterpret_cast<float2*>(h + (size_t)n * 128 + 2 * lane) = o;
}

// ---------------- dense GEMM 2: z2 = h @ W2  (50000x128 @ 128x64) ----------------
// Lane = output feature. W2 in LDS as float2: Wp[kk*64+l] = {W2[2kk][l], W2[2kk+1][l]}.
__global__ __launch_bounds__(256, 4) void gemm2(
    const float* __restrict__ h, const float* __restrict__ W2,
    float* __restrict__ z2) {
  __shared__ float2 Wp[64 * 64];  // 32 KB
  for (int idx = threadIdx.x; idx < 64 * 64; idx += 256) {
    const int kk = idx >> 6, l = idx & 63;
    Wp[idx] = make_float2(W2[(size_t)(2 * kk) * 64 + l], W2[(size_t)(2 * kk + 1) * 64 + l]);
  }
  __syncthreads();

  const int lane = threadIdx.x & 63;
  const int wid  = threadIdx.x >> 6;
  const int n0 = (blockIdx.x * 4 + wid) * 4;  // 3125 blocks * 16 = 50000 exact

  float rx[4], ry[4];
#pragma unroll
  for (int i = 0; i < 4; ++i) {
    const float2 v = *reinterpret_cast<const float2*>(h + (size_t)(n0 + i) * 128 + 2 * lane);
    rx[i] = v.x; ry[i] = v.y;
  }
  float acc[4] = {0.f, 0.f, 0.f, 0.f};
#pragma unroll
  for (int kk = 0; kk < 64; ++kk) {
    const float2 w = Wp[kk * 64 + lane];
#pragma unroll
    for (int i = 0; i < 4; ++i) {
      const float v0 = __int_as_float(__builtin_amdgcn_readlane(__float_as_int(rx[i]), kk));
      const float v1 = __int_as_float(__builtin_amdgcn_readlane(__float_as_int(ry[i]), kk));
      acc[i] = fmaf(v0, w.x, acc[i]);
      acc[i] = fmaf(v1, w.y, acc[i]);
    }
  }
#pragma unroll
  for (int i = 0; i < 4; ++i)
    z2[(size_t)(n0 + i) * 64 + lane] = acc[i];
}

// ---------------- agg2: out = z2[n] + sum z2[adj] + b2 (width 64) ----------------
__global__ __launch_bounds__(256, 8) void agg_out(
    const float* __restrict__ z2, const int* __restrict__ adj,
    const int* __restrict__ cnt, const float* __restrict__ b2,
    const float* __restrict__ zrow, float* __restrict__ out) {
  const int lane = threadIdx.x & 63;
  const int wid  = threadIdx.x >> 6;
  const int n = blockIdx.x * 4 + wid;

  const int va = adj[(size_t)n * kCap + lane];
  int d = __builtin_amdgcn_readfirstlane(cnt[n]);
  if (d > kCap) d = kCap;

  float a0 = z2[(size_t)n * 64 + lane];  // self
  float a1 = 0.f, a2 = 0.f, a3 = 0.f;

  int e = 0;
  while (e < d) {
#pragma unroll
    for (int j = 0; j < 16; ++j) {
      const int ee = e + j;
      const int idx = __builtin_amdgcn_readlane(va, ee);
      const float* base = (ee < d) ? (z2 + (size_t)idx * 64) : zrow;  // scalar select
      const float v = base[lane];
      if ((j & 3) == 0)      a0 += v;
      else if ((j & 3) == 1) a1 += v;
      else if ((j & 3) == 2) a2 += v;
      else                   a3 += v;
    }
    e += 16;
  }

  out[(size_t)n * 64 + lane] = (a0 + a1) + (a2 + a3) + b2[lane];
}

// ---------------- launch ----------------
extern "C" void kernel_launch(void* const* d_in, const int* in_sizes, int n_in,
                              void* d_out, int out_size, void* d_ws, size_t ws_size,
                              hipStream_t stream) {
  const float* x  = (const float*)d_in[0];
  const int*   ei = (const int*)d_in[1];
  const float* W1 = (const float*)d_in[2];
  const float* b1 = (const float*)d_in[3];
  const float* W2 = (const float*)d_in[4];
  const float* b2 = (const float*)d_in[5];
  float* out = (float*)d_out;

  const int E = in_sizes[1] / 2;  // edge_index is (2, E), int32 on device
  const int* src = ei;
  const int* dst = ei + E;

  // d_ws layout (re-poisoned to 0xAA before each launch):
  float* zrow = (float*)d_ws;                       // 128 f32 = 512 B, zeroed
  int*   cnt  = (int*)(zrow + 128);                 // 50000 ints
  int*   adj  = cnt + kN;                           // 50000*64 ints = 12.8 MB
  float* h    = (float*)(adj + (size_t)kN * kCap);  // 50000*128 f32 = 25.6 MB
  float* z1   = h + (size_t)kN * 128;               // 50000*128 f32 = 25.6 MB
  float* z2   = z1;                                 // alias: z1 dead after agg1

  hipMemsetAsync(d_ws, 0, 512 + (size_t)kN * sizeof(int), stream);  // zrow + cnt
  build_adj<<<(E + 255) / 256, 256, 0, stream>>>(src, dst, cnt, adj, E);
  gemm1<<<3125, 256, 0, stream>>>(x, W1, z1);
  agg_relu_drop<<<12500, 256, 0, stream>>>(z1, adj, cnt, b1, zrow, h);
  gemm2<<<3125, 256, 0, stream>>>(h, W2, z2);
  agg_out<<<12500, 256, 0, stream>>>(z2, adj, cnt, b2, zrow, out);
}